// Round 1
// baseline (182.489 us; speedup 1.0000x reference)
//
#include <hip/hip_runtime.h>
#include <hip/hip_fp16.h>

// WHTConv2D: out = Rw(Rh(g(Rh(Rw(x))))) + x
//   Rw/Rh = normalized FWHT-256 along w/h (separable -> order swapped vs ref, exact in math)
//   g(f)[h,w] = sum_p tanh(f*v_p) * relu(|f*v_p| - |T_p|)
// x: (8,64,256,256) f32; v,T: (4,256,256) f32; out f32 same shape as x.

#define NROWS (8 * 64 * 256)   // 131072 rows of 256
#define NPX   65536            // pixels per image

__device__ __forceinline__ unsigned int h2u(__half2 h) {
  union { __half2 h; unsigned int u; } c; c.h = h; return c.u;
}
__device__ __forceinline__ __half2 u2h(unsigned int u) {
  union { __half2 h; unsigned int u; } c; c.u = u; return c.h;
}

// 16-point unnormalized FWHT fully in registers (4 stages of fma-adds).
__device__ __forceinline__ void fwht16(float f[16]) {
  #pragma unroll
  for (int d = 1; d < 16; d <<= 1) {
    #pragma unroll
    for (int i = 0; i < 16; ++i) {
      if (!(i & d)) {
        float a = f[i], b = f[i | d];
        f[i]     = a + b;
        f[i | d] = a - b;
      }
    }
  }
}

// 256-point unnormalized FWHT across one wave; lane holds elems i = 4*lane + j.
// d=1,2 in-register; d=4..128 -> shfl_xor masks 1..32 with sign-fma (no cndmask).
__device__ __forceinline__ void fwht256_wave(float r[4], int lane) {
  float a0 = r[0] + r[1], b0 = r[0] - r[1];
  float a1 = r[2] + r[3], b1 = r[2] - r[3];
  r[0] = a0 + a1; r[1] = b0 + b1; r[2] = a0 - a1; r[3] = b0 - b1;
  #pragma unroll
  for (int m = 1; m <= 32; m <<= 1) {
    const float s = (lane & m) ? -1.0f : 1.0f;
    #pragma unroll
    for (int j = 0; j < 4; ++j) {
      float t = __shfl_xor(r[j], m);
      r[j] = fmaf(r[j], s, t);   // low lane: r+t ; high lane: t-r
    }
  }
}

// one term of g: tanh(a) * relu(|a| - |T|)
__device__ __forceinline__ float g_term(float a, float absT) {
  float ax = fabsf(a);
  float rl = fmaxf(ax - absT, 0.0f);
  // tanh(ax) = 1 - 2/(exp2(2*log2e*ax)+1)
  float e  = __builtin_amdgcn_exp2f(ax * 2.8853900817779268f);
  float th = 1.0f - 2.0f * __builtin_amdgcn_rcpf(e + 1.0f);
  return copysignf(th, a) * rl;
}

// ---------------- kernel 1: row FWHT of x -> t1 (fp16), scaled 1/16 ----------------
__global__ __launch_bounds__(256) void k_row_fwd(const float* __restrict__ x,
                                                 __half* __restrict__ t1) {
  const int lane = threadIdx.x & 63;
  const int wave = blockIdx.x * (blockDim.x >> 6) + (threadIdx.x >> 6);
  const int nw   = gridDim.x * (blockDim.x >> 6);
  for (int row = wave; row < NROWS; row += nw) {
    const float4 xv = *reinterpret_cast<const float4*>(x + (size_t)row * 256 + lane * 4);
    float r[4] = {xv.x, xv.y, xv.z, xv.w};
    fwht256_wave(r, lane);
    const float SC = 0.0625f;
    uint2 pk;
    pk.x = h2u(__floats2half2_rn(r[0] * SC, r[1] * SC));
    pk.y = h2u(__floats2half2_rn(r[2] * SC, r[3] * SC));
    *reinterpret_cast<uint2*>(t1 + (size_t)row * 256 + lane * 4) = pk;
  }
}

// ---------------- kernel 2: column Rh o g o Rh on 256x64 tiles ----------------
// H256 = H16 (x) H16 over h = 16a + k. Pass over k = contiguous rows, pass over
// a = stride-16 rows. Thread (q = tid&15 -> cols 4q..4q+3, g = tid>>4).
// t2 may alias t1 (each block reads its whole tile before writing it).
__global__ __launch_bounds__(256) void k_col(const __half* t1, __half* t2,
                                             const float* __restrict__ v,
                                             const float* __restrict__ T) {
  __shared__ __align__(16) __half lds[256][72];   // 36,864 B; bank-conflict-free
  const int tid = threadIdx.x;
  const int q   = tid & 15;
  const int g   = tid >> 4;
  const int img = blockIdx.x >> 2;
  const int w0  = (blockIdx.x & 3) * 64;
  const int wq  = w0 + 4 * q;
  const size_t ibase = (size_t)img * NPX;
  const float SC = 0.0625f;

  float f[4][16];

  // ---- phase b: load t1 rows 16g..16g+15, FWHT16 over k (low bits), to LDS ----
  #pragma unroll
  for (int k = 0; k < 16; ++k) {
    const int h = 16 * g + k;
    uint2 d = *reinterpret_cast<const uint2*>(t1 + ibase + (size_t)h * 256 + wq);
    float2 lo = __half22float2(u2h(d.x));
    float2 hi = __half22float2(u2h(d.y));
    f[0][k] = lo.x; f[1][k] = lo.y; f[2][k] = hi.x; f[3][k] = hi.y;
  }
  #pragma unroll
  for (int c = 0; c < 4; ++c) fwht16(f[c]);
  #pragma unroll
  for (int k = 0; k < 16; ++k) {
    const int h = 16 * g + k;
    uint2 d;
    d.x = h2u(__floats2half2_rn(f[0][k], f[1][k]));
    d.y = h2u(__floats2half2_rn(f[2][k], f[3][k]));
    *reinterpret_cast<uint2*>(&lds[h][4 * q]) = d;
  }
  __syncthreads();

  // ---- phase c: strided rows h = g + 16a: FWHT16 over a -> f2 (x1/16) -> g ->
  //      FWHT16 over a (Rh2 pass A) -> x1/16 -> back to LDS ----
  #pragma unroll
  for (int a = 0; a < 16; ++a) {
    const int h = g + 16 * a;
    uint2 d = *reinterpret_cast<uint2*>(&lds[h][4 * q]);
    float2 lo = __half22float2(u2h(d.x));
    float2 hi = __half22float2(u2h(d.y));
    f[0][a] = lo.x; f[1][a] = lo.y; f[2][a] = hi.x; f[3][a] = hi.y;
  }
  #pragma unroll
  for (int c = 0; c < 4; ++c) fwht16(f[c]);   // completes Rh1 (unnormalized)
  #pragma unroll
  for (int c = 0; c < 4; ++c)
    #pragma unroll
    for (int a = 0; a < 16; ++a) f[c][a] *= SC;   // Rh1 normalization

  #pragma unroll
  for (int a = 0; a < 16; ++a) {
    const int h = g + 16 * a;
    const size_t off = (size_t)h * 256 + wq;
    float acc0 = 0.f, acc1 = 0.f, acc2 = 0.f, acc3 = 0.f;
    #pragma unroll
    for (int p = 0; p < 4; ++p) {
      const float4 vv = *reinterpret_cast<const float4*>(v + (size_t)p * NPX + off);
      const float4 tt = *reinterpret_cast<const float4*>(T + (size_t)p * NPX + off);
      acc0 += g_term(f[0][a] * vv.x, fabsf(tt.x));
      acc1 += g_term(f[1][a] * vv.y, fabsf(tt.y));
      acc2 += g_term(f[2][a] * vv.z, fabsf(tt.z));
      acc3 += g_term(f[3][a] * vv.w, fabsf(tt.w));
    }
    f[0][a] = acc0; f[1][a] = acc1; f[2][a] = acc2; f[3][a] = acc3;
  }
  #pragma unroll
  for (int c = 0; c < 4; ++c) fwht16(f[c]);   // Rh2 pass over a
  #pragma unroll
  for (int c = 0; c < 4; ++c)
    #pragma unroll
    for (int a = 0; a < 16; ++a) f[c][a] *= SC;   // Rh2 normalization

  #pragma unroll
  for (int a = 0; a < 16; ++a) {
    const int h = g + 16 * a;
    uint2 d;
    d.x = h2u(__floats2half2_rn(f[0][a], f[1][a]));
    d.y = h2u(__floats2half2_rn(f[2][a], f[3][a]));
    *reinterpret_cast<uint2*>(&lds[h][4 * q]) = d;
  }
  __syncthreads();

  // ---- phase d: contiguous rows, FWHT16 over k (Rh2 pass B), store t2 ----
  #pragma unroll
  for (int k = 0; k < 16; ++k) {
    const int h = 16 * g + k;
    uint2 d = *reinterpret_cast<uint2*>(&lds[h][4 * q]);
    float2 lo = __half22float2(u2h(d.x));
    float2 hi = __half22float2(u2h(d.y));
    f[0][k] = lo.x; f[1][k] = lo.y; f[2][k] = hi.x; f[3][k] = hi.y;
  }
  #pragma unroll
  for (int c = 0; c < 4; ++c) fwht16(f[c]);
  #pragma unroll
  for (int k = 0; k < 16; ++k) {
    const int h = 16 * g + k;
    uint2 d;
    d.x = h2u(__floats2half2_rn(f[0][k], f[1][k]));
    d.y = h2u(__floats2half2_rn(f[2][k], f[3][k]));
    *reinterpret_cast<uint2*>(t2 + ibase + (size_t)h * 256 + wq) = d;
  }
}

// ---------------- kernel 3: row FWHT of t2 (x1/16) + x residual -> out ----------------
__global__ __launch_bounds__(256) void k_row_bwd(const __half* __restrict__ t2,
                                                 const float* __restrict__ x,
                                                 float* __restrict__ out) {
  const int lane = threadIdx.x & 63;
  const int wave = blockIdx.x * (blockDim.x >> 6) + (threadIdx.x >> 6);
  const int nw   = gridDim.x * (blockDim.x >> 6);
  for (int row = wave; row < NROWS; row += nw) {
    uint2 pk = *reinterpret_cast<const uint2*>(t2 + (size_t)row * 256 + lane * 4);
    float2 lo = __half22float2(u2h(pk.x));
    float2 hi = __half22float2(u2h(pk.y));
    float r[4] = {lo.x, lo.y, hi.x, hi.y};
    fwht256_wave(r, lane);
    const float4 xv = *reinterpret_cast<const float4*>(x + (size_t)row * 256 + lane * 4);
    const float SC = 0.0625f;
    float4 o;
    o.x = fmaf(r[0], SC, xv.x);
    o.y = fmaf(r[1], SC, xv.y);
    o.z = fmaf(r[2], SC, xv.z);
    o.w = fmaf(r[3], SC, xv.w);
    *reinterpret_cast<float4*>(out + (size_t)row * 256 + lane * 4) = o;
  }
}

extern "C" void kernel_launch(void* const* d_in, const int* in_sizes, int n_in,
                              void* d_out, int out_size, void* d_ws, size_t ws_size,
                              hipStream_t stream) {
  const float* x = (const float*)d_in[0];
  const float* v = (const float*)d_in[1];
  const float* T = (const float*)d_in[2];
  float* out = (float*)d_out;
  __half* t1 = (__half*)d_ws;   // 64 MB fp16 intermediate; k_col runs in place

  k_row_fwd<<<2048, 256, 0, stream>>>(x, t1);
  k_col<<<2048, 256, 0, stream>>>(t1, t1, v, T);
  k_row_bwd<<<2048, 256, 0, stream>>>(t1, x, out);
}